// Round 1
// baseline (745.414 us; speedup 1.0000x reference)
//
#include <hip/hip_runtime.h>
#include <hip/hip_bf16.h>
#include <cstdint>
#include <cstddef>

#define IN_DIM 4096
#define OUT_DIM 4096
#define NTOK 8192
#define PLANE (IN_DIM * OUT_DIM)

typedef __bf16 bf16x8_t __attribute__((ext_vector_type(8)));
typedef float f32x4_t __attribute__((ext_vector_type(4)));

__device__ inline void async_load16(void* lds, const void* g) {
    __builtin_amdgcn_global_load_lds(
        (const __attribute__((address_space(1))) char*)g,
        (__attribute__((address_space(3))) char*)lds,
        16, 0, 0);
}

__device__ inline unsigned short f2bf(float f) {
    __hip_bfloat16 h = __float2bfloat16(f);
    return *(unsigned short*)&h;
}

// Pass 1: decode bit planes -> signed code s*k, write W^T (unscaled, exact in
// bf16) via LDS transpose, and block-reduce sum(k^2), sum(s*k) for the std.
__global__ void pack_kernel(const float* __restrict__ mag,
                            const float* __restrict__ sgn,
                            unsigned short* __restrict__ wT,
                            int* __restrict__ sums) {
    __shared__ short tile[64 * 65];   // [i_local][o_local], pad 65 vs transpose
    __shared__ int red2[4], reds[4];
    const int t = threadIdx.x;
    const int o0 = blockIdx.x * 64, i0 = blockIdx.y * 64;
    const int olo = t & 63, ibase = t >> 6;
    int lk2 = 0, lsk = 0;
    #pragma unroll
    for (int r = 0; r < 16; ++r) {
        const int ilo = ibase + r * 4;
        const int idx = (i0 + ilo) * OUT_DIM + o0 + olo;
        const float m0 = mag[idx];
        const float m1 = mag[idx + PLANE];
        const float m2 = mag[idx + 2 * PLANE];
        const float sv = sgn[idx];
        const int k = ((m0 >= 0.f) ? 4 : 0) | ((m1 >= 0.f) ? 2 : 0) | ((m2 >= 0.f) ? 1 : 0);
        const int code = (sv >= 0.f) ? k : -k;
        lk2 += k * k;
        lsk += code;
        tile[ilo * 65 + olo] = (short)code;
    }
    // wave reduce (64 lanes), then cross-wave via LDS
    #pragma unroll
    for (int off = 32; off > 0; off >>= 1) {
        lk2 += __shfl_down(lk2, off);
        lsk += __shfl_down(lsk, off);
    }
    const int wv = t >> 6, ln = t & 63;
    if (ln == 0) { red2[wv] = lk2; reds[wv] = lsk; }
    __syncthreads();
    if (t == 0) {
        atomicAdd(&sums[0], red2[0] + red2[1] + red2[2] + red2[3]);
        atomicAdd(&sums[1], reds[0] + reds[1] + reds[2] + reds[3]);
    }
    // transposed write: wT[o][i], lanes contiguous along i
    const int ilo = t & 63, obase = t >> 6;
    #pragma unroll
    for (int r = 0; r < 16; ++r) {
        const int olo2 = obase + r * 4;
        const float v = (float)tile[ilo * 65 + olo2] * 0.125f;  // exact in bf16
        wT[(size_t)(o0 + olo2) * IN_DIM + i0 + ilo] = f2bf(v);
    }
}

__global__ void alpha_kernel(const int* __restrict__ sums, float* __restrict__ alpha) {
    const double n = (double)PLANE;
    const double mean = (double)sums[1] / (8.0 * n);
    const double e2 = (double)sums[0] / (64.0 * n);
    const double var = e2 - mean * mean;
    const double sd = sqrt(var);
    *alpha = (float)(sqrt(2.0 / (double)IN_DIM) / (sd + 1e-12));
}

__global__ void cvt_kernel(const float* __restrict__ x, unsigned short* __restrict__ xb) {
    const int idx = blockIdx.x * blockDim.x + threadIdx.x;
    const float4 v = ((const float4*)x)[idx];
    ushort4 o;
    o.x = f2bf(v.x);
    o.y = f2bf(v.y);
    o.z = f2bf(v.z);
    o.w = f2bf(v.w);
    ((ushort4*)xb)[idx] = o;
}

// m97-structure GEMM: C[M,N] = A[M,K] * B^T[N,K], bf16 MFMA 16x16x32,
// 128x128 block tile, BK=32, global_load_lds width-16 staging, epilogue *alpha.
__global__ __launch_bounds__(256) void gemm_kernel(const unsigned short* __restrict__ A,
                                                   const unsigned short* __restrict__ B,
                                                   float* __restrict__ C,
                                                   const float* __restrict__ alphap) {
    __shared__ __align__(16) unsigned short As[128 * 32];
    __shared__ __align__(16) unsigned short Bs[128 * 32];
    const int t = threadIdx.x;
    const int lane = t & 63, wave = t >> 6;
    const int wm = wave >> 1, wn = wave & 1;
    const int m0 = blockIdx.y * 128, n0 = blockIdx.x * 128;
    const int r15 = lane & 15, q = lane >> 4;

    f32x4_t acc[4][4] = {};

    int aoff[4], boff[4];
    #pragma unroll
    for (int i = 0; i < 4; ++i) {
        aoff[i] = (wm * 64 + i * 16 + r15) * 32 + q * 8;
        boff[i] = (wn * 64 + i * 16 + r15) * 32 + q * 8;
    }

    const int c0 = t, c1 = t + 256;
    const int row0 = c0 >> 2, cb0 = (c0 & 3) * 16;
    const int row1 = c1 >> 2, cb1 = (c1 & 3) * 16;

    for (int k0 = 0; k0 < IN_DIM; k0 += 32) {
        async_load16(&As[c0 * 8], (const char*)(A + (size_t)(m0 + row0) * IN_DIM + k0) + cb0);
        async_load16(&As[c1 * 8], (const char*)(A + (size_t)(m0 + row1) * IN_DIM + k0) + cb1);
        async_load16(&Bs[c0 * 8], (const char*)(B + (size_t)(n0 + row0) * IN_DIM + k0) + cb0);
        async_load16(&Bs[c1 * 8], (const char*)(B + (size_t)(n0 + row1) * IN_DIM + k0) + cb1);
        __syncthreads();
        bf16x8_t a[4], b[4];
        #pragma unroll
        for (int i = 0; i < 4; ++i) a[i] = *(const bf16x8_t*)&As[aoff[i]];
        #pragma unroll
        for (int i = 0; i < 4; ++i) b[i] = *(const bf16x8_t*)&Bs[boff[i]];
        #pragma unroll
        for (int mt = 0; mt < 4; ++mt)
            #pragma unroll
            for (int nt = 0; nt < 4; ++nt)
                acc[mt][nt] = __builtin_amdgcn_mfma_f32_16x16x32_bf16(a[mt], b[nt], acc[mt][nt], 0, 0, 0);
        __syncthreads();
    }

    const float alpha = *alphap;
    #pragma unroll
    for (int mt = 0; mt < 4; ++mt) {
        const int mbase = m0 + wm * 64 + mt * 16 + q * 4;
        #pragma unroll
        for (int nt = 0; nt < 4; ++nt) {
            const int n = n0 + wn * 64 + nt * 16 + r15;
            float* cp = C + (size_t)mbase * OUT_DIM + n;
            cp[0 * OUT_DIM] = acc[mt][nt][0] * alpha;
            cp[1 * OUT_DIM] = acc[mt][nt][1] * alpha;
            cp[2 * OUT_DIM] = acc[mt][nt][2] * alpha;
            cp[3 * OUT_DIM] = acc[mt][nt][3] * alpha;
        }
    }
}

extern "C" void kernel_launch(void* const* d_in, const int* in_sizes, int n_in,
                              void* d_out, int out_size, void* d_ws, size_t ws_size,
                              hipStream_t stream) {
    const float* x   = (const float*)d_in[0];
    const float* mag = (const float*)d_in[1];
    const float* sgn = (const float*)d_in[2];
    float* out = (float*)d_out;

    char* ws = (char*)d_ws;
    int* sums = (int*)ws;                                    // [0]=sum k^2, [1]=sum s*k
    float* alphap = (float*)(ws + 8);
    unsigned short* wT = (unsigned short*)(ws + 256);        // [OUT_DIM][IN_DIM] bf16
    unsigned short* xb = (unsigned short*)(ws + 256 + (size_t)PLANE * 2);  // [NTOK][IN_DIM] bf16

    hipMemsetAsync(d_ws, 0, 16, stream);
    pack_kernel<<<dim3(OUT_DIM / 64, IN_DIM / 64), 256, 0, stream>>>(mag, sgn, wT, sums);
    alpha_kernel<<<1, 1, 0, stream>>>(sums, alphap);
    cvt_kernel<<<(NTOK * IN_DIM) / 1024, 256, 0, stream>>>(x, xb);
    gemm_kernel<<<dim3(OUT_DIM / 128, NTOK / 128), 256, 0, stream>>>(xb, wT, out, alphap);
}

// Round 2
// 727.785 us; speedup vs baseline: 1.0242x; 1.0242x over previous
//
#include <hip/hip_runtime.h>
#include <hip/hip_bf16.h>
#include <cstdint>
#include <cstddef>

#define IN_DIM 4096
#define OUT_DIM 4096
#define NTOK 8192
#define PLANE (IN_DIM * OUT_DIM)
#define NPACK_BLOCKS 4096

typedef __bf16 bf16x8_t __attribute__((ext_vector_type(8)));
typedef float f32x4_t __attribute__((ext_vector_type(4)));

__device__ inline void async_load16(void* lds, const void* g) {
    __builtin_amdgcn_global_load_lds(
        (const __attribute__((address_space(1))) char*)g,
        (__attribute__((address_space(3))) char*)lds,
        16, 0, 0);
}

__device__ inline unsigned short f2bf(float f) {
    __hip_bfloat16 h = __float2bfloat16(f);
    return *(unsigned short*)&h;
}

// Pass 1: decode bit planes -> signed code s*k (exact in bf16 as k/8),
// write W^T via LDS transpose, and emit PER-BLOCK partial sums (no atomics:
// 8192 same-address device atomics across 8 XCDs cost ~300us in R1).
__global__ __launch_bounds__(256) void pack_kernel(const float* __restrict__ mag,
                                                   const float* __restrict__ sgn,
                                                   unsigned short* __restrict__ wT,
                                                   int* __restrict__ partials) {
    __shared__ short tile[64 * 68];   // [i_local][o_local], stride 68 (8B-aligned rows)
    __shared__ int red2[4], reds[4];
    const int t = threadIdx.x;
    const int o0 = blockIdx.x * 64, i0 = blockIdx.y * 64;
    const int oq = t & 15, ir = t >> 4;
    int lk2 = 0, lsk = 0;
    #pragma unroll
    for (int r = 0; r < 4; ++r) {
        const int ilo = r * 16 + ir;
        const size_t idx = (size_t)(i0 + ilo) * OUT_DIM + o0 + oq * 4;
        const float4 m0 = *(const float4*)(mag + idx);
        const float4 m1 = *(const float4*)(mag + idx + (size_t)PLANE);
        const float4 m2 = *(const float4*)(mag + idx + 2 * (size_t)PLANE);
        const float4 sv = *(const float4*)(sgn + idx);
        short4 c;
        {
            int k = ((m0.x >= 0.f) ? 4 : 0) | ((m1.x >= 0.f) ? 2 : 0) | ((m2.x >= 0.f) ? 1 : 0);
            int cd = (sv.x >= 0.f) ? k : -k; lk2 += k * k; lsk += cd; c.x = (short)cd;
        }
        {
            int k = ((m0.y >= 0.f) ? 4 : 0) | ((m1.y >= 0.f) ? 2 : 0) | ((m2.y >= 0.f) ? 1 : 0);
            int cd = (sv.y >= 0.f) ? k : -k; lk2 += k * k; lsk += cd; c.y = (short)cd;
        }
        {
            int k = ((m0.z >= 0.f) ? 4 : 0) | ((m1.z >= 0.f) ? 2 : 0) | ((m2.z >= 0.f) ? 1 : 0);
            int cd = (sv.z >= 0.f) ? k : -k; lk2 += k * k; lsk += cd; c.z = (short)cd;
        }
        {
            int k = ((m0.w >= 0.f) ? 4 : 0) | ((m1.w >= 0.f) ? 2 : 0) | ((m2.w >= 0.f) ? 1 : 0);
            int cd = (sv.w >= 0.f) ? k : -k; lk2 += k * k; lsk += cd; c.w = (short)cd;
        }
        *(short4*)&tile[ilo * 68 + oq * 4] = c;
    }
    // wave reduce (64 lanes), then cross-wave via LDS, single store per block
    #pragma unroll
    for (int off = 32; off > 0; off >>= 1) {
        lk2 += __shfl_down(lk2, off);
        lsk += __shfl_down(lsk, off);
    }
    const int wv = t >> 6, ln = t & 63;
    if (ln == 0) { red2[wv] = lk2; reds[wv] = lsk; }
    __syncthreads();
    if (t == 0) {
        const int bid = blockIdx.y * gridDim.x + blockIdx.x;
        partials[bid] = red2[0] + red2[1] + red2[2] + red2[3];
        partials[NPACK_BLOCKS + bid] = reds[0] + reds[1] + reds[2] + reds[3];
    }
    // transposed write: wT[o][i], ushort4 along i (8B stores, coalesced)
    const int iq = t & 15, orr = t >> 4;
    #pragma unroll
    for (int r = 0; r < 4; ++r) {
        const int olo = r * 16 + orr;
        ushort4 w4;
        w4.x = f2bf((float)tile[(iq * 4 + 0) * 68 + olo] * 0.125f);
        w4.y = f2bf((float)tile[(iq * 4 + 1) * 68 + olo] * 0.125f);
        w4.z = f2bf((float)tile[(iq * 4 + 2) * 68 + olo] * 0.125f);
        w4.w = f2bf((float)tile[(iq * 4 + 3) * 68 + olo] * 0.125f);
        *(ushort4*)&wT[(size_t)(o0 + olo) * IN_DIM + i0 + iq * 4] = w4;
    }
}

// Reduce the 4096 partial pairs and compute alpha. One block.
__global__ __launch_bounds__(256) void alpha_kernel(const int* __restrict__ partials,
                                                    float* __restrict__ alpha) {
    __shared__ int red2[4], reds[4];
    const int t = threadIdx.x;
    int k2 = 0, sk = 0;
    for (int i = t; i < NPACK_BLOCKS; i += 256) {
        k2 += partials[i];
        sk += partials[NPACK_BLOCKS + i];
    }
    #pragma unroll
    for (int off = 32; off > 0; off >>= 1) {
        k2 += __shfl_down(k2, off);
        sk += __shfl_down(sk, off);
    }
    const int wv = t >> 6, ln = t & 63;
    if (ln == 0) { red2[wv] = k2; reds[wv] = sk; }
    __syncthreads();
    if (t == 0) {
        const double n = (double)PLANE;
        const double sumk2 = (double)(red2[0] + red2[1] + red2[2] + red2[3]);
        const double sumsk = (double)(reds[0] + reds[1] + reds[2] + reds[3]);
        const double mean = sumsk / (8.0 * n);
        const double e2 = sumk2 / (64.0 * n);
        const double sd = sqrt(e2 - mean * mean);
        *alpha = (float)(sqrt(2.0 / (double)IN_DIM) / (sd + 1e-12));
    }
}

__global__ __launch_bounds__(256) void cvt_kernel(const float* __restrict__ x,
                                                  unsigned short* __restrict__ xb) {
    const int idx = blockIdx.x * blockDim.x + threadIdx.x;
    const float4 v = ((const float4*)x)[idx];
    ushort4 o;
    o.x = f2bf(v.x);
    o.y = f2bf(v.y);
    o.z = f2bf(v.z);
    o.w = f2bf(v.w);
    ((ushort4*)xb)[idx] = o;
}

// m97-structure GEMM: C[M,N] = A[M,K] * B^T[N,K], bf16 MFMA 16x16x32,
// 128x128 block tile, BK=32, global_load_lds width-16 staging, epilogue *alpha.
__global__ __launch_bounds__(256) void gemm_kernel(const unsigned short* __restrict__ A,
                                                   const unsigned short* __restrict__ B,
                                                   float* __restrict__ C,
                                                   const float* __restrict__ alphap) {
    __shared__ __align__(16) unsigned short As[128 * 32];
    __shared__ __align__(16) unsigned short Bs[128 * 32];
    const int t = threadIdx.x;
    const int lane = t & 63, wave = t >> 6;
    const int wm = wave >> 1, wn = wave & 1;
    const int m0 = blockIdx.y * 128, n0 = blockIdx.x * 128;
    const int r15 = lane & 15, q = lane >> 4;

    f32x4_t acc[4][4] = {};

    int aoff[4], boff[4];
    #pragma unroll
    for (int i = 0; i < 4; ++i) {
        aoff[i] = (wm * 64 + i * 16 + r15) * 32 + q * 8;
        boff[i] = (wn * 64 + i * 16 + r15) * 32 + q * 8;
    }

    const int c0 = t, c1 = t + 256;
    const int row0 = c0 >> 2, cb0 = (c0 & 3) * 16;
    const int row1 = c1 >> 2, cb1 = (c1 & 3) * 16;

    for (int k0 = 0; k0 < IN_DIM; k0 += 32) {
        async_load16(&As[c0 * 8], (const char*)(A + (size_t)(m0 + row0) * IN_DIM + k0) + cb0);
        async_load16(&As[c1 * 8], (const char*)(A + (size_t)(m0 + row1) * IN_DIM + k0) + cb1);
        async_load16(&Bs[c0 * 8], (const char*)(B + (size_t)(n0 + row0) * IN_DIM + k0) + cb0);
        async_load16(&Bs[c1 * 8], (const char*)(B + (size_t)(n0 + row1) * IN_DIM + k0) + cb1);
        __syncthreads();
        bf16x8_t a[4], b[4];
        #pragma unroll
        for (int i = 0; i < 4; ++i) a[i] = *(const bf16x8_t*)&As[aoff[i]];
        #pragma unroll
        for (int i = 0; i < 4; ++i) b[i] = *(const bf16x8_t*)&Bs[boff[i]];
        #pragma unroll
        for (int mt = 0; mt < 4; ++mt)
            #pragma unroll
            for (int nt = 0; nt < 4; ++nt)
                acc[mt][nt] = __builtin_amdgcn_mfma_f32_16x16x32_bf16(a[mt], b[nt], acc[mt][nt], 0, 0, 0);
        __syncthreads();
    }

    const float alpha = *alphap;
    #pragma unroll
    for (int mt = 0; mt < 4; ++mt) {
        const int mbase = m0 + wm * 64 + mt * 16 + q * 4;
        #pragma unroll
        for (int nt = 0; nt < 4; ++nt) {
            const int n = n0 + wn * 64 + nt * 16 + r15;
            float* cp = C + (size_t)mbase * OUT_DIM + n;
            cp[0 * OUT_DIM] = acc[mt][nt][0] * alpha;
            cp[1 * OUT_DIM] = acc[mt][nt][1] * alpha;
            cp[2 * OUT_DIM] = acc[mt][nt][2] * alpha;
            cp[3 * OUT_DIM] = acc[mt][nt][3] * alpha;
        }
    }
}

extern "C" void kernel_launch(void* const* d_in, const int* in_sizes, int n_in,
                              void* d_out, int out_size, void* d_ws, size_t ws_size,
                              hipStream_t stream) {
    const float* x   = (const float*)d_in[0];
    const float* mag = (const float*)d_in[1];
    const float* sgn = (const float*)d_in[2];
    float* out = (float*)d_out;

    char* ws = (char*)d_ws;
    int* partials = (int*)ws;                                 // 2*4096 ints = 32 KB
    float* alphap = (float*)(ws + 32768);
    unsigned short* wT = (unsigned short*)(ws + 65536);       // [OUT_DIM][IN_DIM] bf16
    unsigned short* xb = (unsigned short*)(ws + 65536 + (size_t)PLANE * 2);  // [NTOK][IN_DIM] bf16

    pack_kernel<<<dim3(OUT_DIM / 64, IN_DIM / 64), 256, 0, stream>>>(mag, sgn, wT, partials);
    alpha_kernel<<<1, 256, 0, stream>>>(partials, alphap);
    cvt_kernel<<<(NTOK * IN_DIM) / 1024, 256, 0, stream>>>(x, xb);
    gemm_kernel<<<dim3(OUT_DIM / 128, NTOK / 128), 256, 0, stream>>>(xb, wT, out, alphap);
}

// Round 3
// 582.261 us; speedup vs baseline: 1.2802x; 1.2499x over previous
//
#include <hip/hip_runtime.h>
#include <hip/hip_bf16.h>
#include <cstdint>
#include <cstddef>

#define IN_DIM 4096
#define OUT_DIM 4096
#define NTOK 8192
#define PLANE (IN_DIM * OUT_DIM)
#define NPACK_BLOCKS 4096

typedef int i32x4_t __attribute__((ext_vector_type(4)));

__device__ inline void async_load16(void* lds, const void* g) {
    __builtin_amdgcn_global_load_lds(
        (const __attribute__((address_space(1))) char*)g,
        (__attribute__((address_space(3))) char*)lds,
        16, 0, 0);
}

// Pass 1: decode bit planes -> signed integer code s*k in [-7,7] (EXACT in i8),
// write W^T as i8 via LDS transpose, emit per-block partial sums for the std.
__global__ __launch_bounds__(256) void pack_kernel(const float* __restrict__ mag,
                                                   const float* __restrict__ sgn,
                                                   signed char* __restrict__ wT,
                                                   int* __restrict__ partials) {
    __shared__ short tile[64 * 68];   // [i_local][o_local], stride 68 keeps 8B-aligned rows
    __shared__ int red2[4], reds[4];
    const int t = threadIdx.x;
    const int o0 = blockIdx.x * 64, i0 = blockIdx.y * 64;
    const int oq = t & 15, ir = t >> 4;
    int lk2 = 0, lsk = 0;
    #pragma unroll
    for (int r = 0; r < 4; ++r) {
        const int ilo = r * 16 + ir;
        const size_t idx = (size_t)(i0 + ilo) * OUT_DIM + o0 + oq * 4;
        const float4 m0 = *(const float4*)(mag + idx);
        const float4 m1 = *(const float4*)(mag + idx + (size_t)PLANE);
        const float4 m2 = *(const float4*)(mag + idx + 2 * (size_t)PLANE);
        const float4 sv = *(const float4*)(sgn + idx);
        short4 c;
        {
            int k = ((m0.x >= 0.f) ? 4 : 0) | ((m1.x >= 0.f) ? 2 : 0) | ((m2.x >= 0.f) ? 1 : 0);
            int cd = (sv.x >= 0.f) ? k : -k; lk2 += k * k; lsk += cd; c.x = (short)cd;
        }
        {
            int k = ((m0.y >= 0.f) ? 4 : 0) | ((m1.y >= 0.f) ? 2 : 0) | ((m2.y >= 0.f) ? 1 : 0);
            int cd = (sv.y >= 0.f) ? k : -k; lk2 += k * k; lsk += cd; c.y = (short)cd;
        }
        {
            int k = ((m0.z >= 0.f) ? 4 : 0) | ((m1.z >= 0.f) ? 2 : 0) | ((m2.z >= 0.f) ? 1 : 0);
            int cd = (sv.z >= 0.f) ? k : -k; lk2 += k * k; lsk += cd; c.z = (short)cd;
        }
        {
            int k = ((m0.w >= 0.f) ? 4 : 0) | ((m1.w >= 0.f) ? 2 : 0) | ((m2.w >= 0.f) ? 1 : 0);
            int cd = (sv.w >= 0.f) ? k : -k; lk2 += k * k; lsk += cd; c.w = (short)cd;
        }
        *(short4*)&tile[ilo * 68 + oq * 4] = c;
    }
    #pragma unroll
    for (int off = 32; off > 0; off >>= 1) {
        lk2 += __shfl_down(lk2, off);
        lsk += __shfl_down(lsk, off);
    }
    const int wv = t >> 6, ln = t & 63;
    if (ln == 0) { red2[wv] = lk2; reds[wv] = lsk; }
    __syncthreads();
    if (t == 0) {
        const int bid = blockIdx.y * gridDim.x + blockIdx.x;
        partials[bid] = red2[0] + red2[1] + red2[2] + red2[3];
        partials[NPACK_BLOCKS + bid] = reds[0] + reds[1] + reds[2] + reds[3];
    }
    // transposed write: wT[o][i] as i8, char4 along i
    const int iq = t & 15, orr = t >> 4;
    #pragma unroll
    for (int r = 0; r < 4; ++r) {
        const int olo = r * 16 + orr;
        char4 w4;
        w4.x = (signed char)tile[(iq * 4 + 0) * 68 + olo];
        w4.y = (signed char)tile[(iq * 4 + 1) * 68 + olo];
        w4.z = (signed char)tile[(iq * 4 + 2) * 68 + olo];
        w4.w = (signed char)tile[(iq * 4 + 3) * 68 + olo];
        *(char4*)&wT[(size_t)(o0 + olo) * IN_DIM + i0 + iq * 4] = w4;
    }
}

// Reduce partial pairs -> alpha/8 (the /8 folds the k/8 magnitude scaling).
__global__ __launch_bounds__(256) void alpha_kernel(const int* __restrict__ partials,
                                                    float* __restrict__ alpha8) {
    __shared__ int red2[4], reds[4];
    const int t = threadIdx.x;
    int k2 = 0, sk = 0;
    for (int i = t; i < NPACK_BLOCKS; i += 256) {
        k2 += partials[i];
        sk += partials[NPACK_BLOCKS + i];
    }
    #pragma unroll
    for (int off = 32; off > 0; off >>= 1) {
        k2 += __shfl_down(k2, off);
        sk += __shfl_down(sk, off);
    }
    const int wv = t >> 6, ln = t & 63;
    if (ln == 0) { red2[wv] = k2; reds[wv] = sk; }
    __syncthreads();
    if (t == 0) {
        const double n = (double)PLANE;
        const double sumk2 = (double)(red2[0] + red2[1] + red2[2] + red2[3]);
        const double sumsk = (double)(reds[0] + reds[1] + reds[2] + reds[3]);
        const double mean = sumsk / (8.0 * n);
        const double e2 = sumk2 / (64.0 * n);
        const double sd = sqrt(e2 - mean * mean);
        *alpha8 = (float)(sqrt(2.0 / (double)IN_DIM) / (sd + 1e-12) * 0.125);
    }
}

// Per-token-row symmetric i8 quantization of x. One block per row.
__global__ __launch_bounds__(256) void quant_kernel(const float* __restrict__ x,
                                                    signed char* __restrict__ xq,
                                                    float* __restrict__ steps) {
    __shared__ float red[4];
    const int r = blockIdx.x, t = threadIdx.x;
    const float* xr = x + (size_t)r * IN_DIM;
    float4 v[4];
    float am = 0.f;
    #pragma unroll
    for (int p = 0; p < 4; ++p) {
        v[p] = ((const float4*)xr)[p * 256 + t];
        am = fmaxf(am, fmaxf(fmaxf(fabsf(v[p].x), fabsf(v[p].y)),
                             fmaxf(fabsf(v[p].z), fabsf(v[p].w))));
    }
    #pragma unroll
    for (int off = 32; off > 0; off >>= 1) am = fmaxf(am, __shfl_down(am, off));
    const int wv = t >> 6, ln = t & 63;
    if (ln == 0) red[wv] = am;
    __syncthreads();
    am = fmaxf(fmaxf(red[0], red[1]), fmaxf(red[2], red[3]));
    am = fmaxf(am, 1e-30f);
    const float rstep = 127.0f / am;
    if (t == 0) steps[r] = am * (1.0f / 127.0f);
    int* xqi = (int*)(xq + (size_t)r * IN_DIM);
    #pragma unroll
    for (int p = 0; p < 4; ++p) {
        const int q0 = (int)rintf(v[p].x * rstep);
        const int q1 = (int)rintf(v[p].y * rstep);
        const int q2 = (int)rintf(v[p].z * rstep);
        const int q3 = (int)rintf(v[p].w * rstep);
        xqi[p * 256 + t] = (q0 & 0xFF) | ((q1 & 0xFF) << 8) | ((q2 & 0xFF) << 16) | (q3 << 24);
    }
}

// i8 GEMM, m97 structure: C[M,N] = A[M,K] * B^T[N,K], mfma_i32_16x16x64_i8,
// 128x128 tile, BK=64 (8KB/tile LDS, same 16KB total as bf16 BK=32), exact i32
// accumulation, epilogue scales by alpha/8 * per-row step.
__global__ __launch_bounds__(256) void gemm_kernel(const signed char* __restrict__ A,
                                                   const signed char* __restrict__ B,
                                                   float* __restrict__ C,
                                                   const float* __restrict__ alphap,
                                                   const float* __restrict__ steps) {
    __shared__ __align__(16) signed char As[128 * 64];
    __shared__ __align__(16) signed char Bs[128 * 64];
    const int t = threadIdx.x;
    const int lane = t & 63, wave = t >> 6;
    const int wm = wave >> 1, wn = wave & 1;
    const int m0 = blockIdx.y * 128, n0 = blockIdx.x * 128;
    const int r15 = lane & 15, q = lane >> 4;

    i32x4_t acc[4][4] = {};

    int aoff[4], boff[4];
    #pragma unroll
    for (int i = 0; i < 4; ++i) {
        aoff[i] = (wm * 64 + i * 16 + r15) * 64 + q * 16;  // byte offsets
        boff[i] = (wn * 64 + i * 16 + r15) * 64 + q * 16;
    }

    const int c0 = t, c1 = t + 256;            // 512 x 16B chunks per 8KB tile
    const int row0 = c0 >> 2, cb0 = (c0 & 3) * 16;
    const int row1 = c1 >> 2, cb1 = (c1 & 3) * 16;

    for (int k0 = 0; k0 < IN_DIM; k0 += 64) {
        async_load16(&As[c0 * 16], A + (size_t)(m0 + row0) * IN_DIM + k0 + cb0);
        async_load16(&As[c1 * 16], A + (size_t)(m0 + row1) * IN_DIM + k0 + cb1);
        async_load16(&Bs[c0 * 16], B + (size_t)(n0 + row0) * IN_DIM + k0 + cb0);
        async_load16(&Bs[c1 * 16], B + (size_t)(n0 + row1) * IN_DIM + k0 + cb1);
        __syncthreads();
        i32x4_t a[4], b[4];
        #pragma unroll
        for (int i = 0; i < 4; ++i) a[i] = *(const i32x4_t*)&As[aoff[i]];
        #pragma unroll
        for (int i = 0; i < 4; ++i) b[i] = *(const i32x4_t*)&Bs[boff[i]];
        #pragma unroll
        for (int mt = 0; mt < 4; ++mt)
            #pragma unroll
            for (int nt = 0; nt < 4; ++nt)
                acc[mt][nt] = __builtin_amdgcn_mfma_i32_16x16x64_i8(a[mt], b[nt], acc[mt][nt], 0, 0, 0);
        __syncthreads();
    }

    const float alpha8 = *alphap;
    #pragma unroll
    for (int mt = 0; mt < 4; ++mt) {
        const int mbase = m0 + wm * 64 + mt * 16 + q * 4;
        const float s0 = alpha8 * steps[mbase + 0];
        const float s1 = alpha8 * steps[mbase + 1];
        const float s2 = alpha8 * steps[mbase + 2];
        const float s3 = alpha8 * steps[mbase + 3];
        #pragma unroll
        for (int nt = 0; nt < 4; ++nt) {
            const int n = n0 + wn * 64 + nt * 16 + r15;
            float* cp = C + (size_t)mbase * OUT_DIM + n;
            cp[0 * OUT_DIM] = (float)acc[mt][nt][0] * s0;  // |acc| < 2^22: exact cvt
            cp[1 * OUT_DIM] = (float)acc[mt][nt][1] * s1;
            cp[2 * OUT_DIM] = (float)acc[mt][nt][2] * s2;
            cp[3 * OUT_DIM] = (float)acc[mt][nt][3] * s3;
        }
    }
}

extern "C" void kernel_launch(void* const* d_in, const int* in_sizes, int n_in,
                              void* d_out, int out_size, void* d_ws, size_t ws_size,
                              hipStream_t stream) {
    const float* x   = (const float*)d_in[0];
    const float* mag = (const float*)d_in[1];
    const float* sgn = (const float*)d_in[2];
    float* out = (float*)d_out;

    char* ws = (char*)d_ws;
    int* partials = (int*)ws;                                  // 32 KB
    float* alphap = (float*)(ws + 32768);
    float* steps  = (float*)(ws + 65536);                      // 8192 floats
    signed char* wT = (signed char*)(ws + 131072);             // [OUT][IN] i8, 16.7 MB
    signed char* xq = (signed char*)(ws + 131072 + (size_t)PLANE);  // [NTOK][IN] i8, 33.5 MB

    pack_kernel<<<dim3(OUT_DIM / 64, IN_DIM / 64), 256, 0, stream>>>(mag, sgn, wT, partials);
    quant_kernel<<<NTOK, 256, 0, stream>>>(x, xq, steps);
    alpha_kernel<<<1, 256, 0, stream>>>(partials, alphap);
    gemm_kernel<<<dim3(OUT_DIM / 128, NTOK / 128), 256, 0, stream>>>(xq, wT, out, alphap, steps);
}